// Round 1
// baseline (140.903 us; speedup 1.0000x reference)
//
#include <hip/hip_runtime.h>

// Problem constants (from reference): T=8192 frames, D=256, P=64 phones, K=128 centers/phone
#define T_FRAMES 8192
#define D_DIM    256
#define P_PHONES 64
#define K_CENT   128

// Kernel 1: norms[p*K + k] = sum_d centers[p][k][d]^2
// One wave (64 lanes) per center; lane i owns float4 at d = 4*i.
__global__ __launch_bounds__(256) void qr_norms_kernel(const float* __restrict__ centers,
                                                       float* __restrict__ norms) {
    const int gwave = (blockIdx.x * blockDim.x + threadIdx.x) >> 6;  // center id in [0, P*K)
    const int lane  = threadIdx.x & 63;
    const float4* c4 = (const float4*)(centers + (size_t)gwave * D_DIM);
    float4 cv = c4[lane];
    float s = cv.x * cv.x + cv.y * cv.y + cv.z * cv.z + cv.w * cv.w;
#pragma unroll
    for (int off = 32; off; off >>= 1) s += __shfl_xor(s, off, 64);
    if (lane == 0) norms[gwave] = s;
}

// Kernel 2: one wave per frame. Lanes span D (float4 each -> coalesced, 1KB/wave
// per center). Per-center full butterfly reduction leaves the dot product
// lane-uniform, so argmin tracking is redundant-per-lane (no final reduce).
// Output = exact fp32 copy of the winning center row.
__global__ __launch_bounds__(256) void qr_retrieve_kernel(const float* __restrict__ h,
                                                          const float* __restrict__ centers,
                                                          const int* __restrict__ phones,
                                                          const float* __restrict__ norms,
                                                          float* __restrict__ out) {
    const int wave = threadIdx.x >> 6;            // 4 waves per block
    const int lane = threadIdx.x & 63;
    const int t    = blockIdx.x * 4 + wave;       // frame id
    if (t >= T_FRAMES) return;

    const int p = phones[t];                      // wave-uniform -> scalar load

    const float4* h4 = (const float4*)(h + (size_t)t * D_DIM);
    const float4 hv = h4[lane];

    const float4* c4  = (const float4*)(centers + (size_t)p * K_CENT * D_DIM);
    const float*  np_ = norms + p * K_CENT;       // wave-uniform base -> s_loads

    float best  = 3.0e38f;
    int   bestk = 0;
#pragma unroll 4
    for (int k = 0; k < K_CENT; ++k) {
        float4 cv = c4[(size_t)k * (D_DIM / 4) + lane];
        float s = hv.x * cv.x + hv.y * cv.y + hv.z * cv.z + hv.w * cv.w;
#pragma unroll
        for (int off = 32; off; off >>= 1) s += __shfl_xor(s, off, 64);
        float d2 = np_[k] - 2.0f * s;             // reference formula, fp32
        if (d2 < best) { best = d2; bestk = k; }  // strict '<' => first-min, matches jnp.argmin
    }

    // Copy winning center row verbatim (exact match when argmin agrees).
    const float4* w4 = (const float4*)(centers + ((size_t)p * K_CENT + bestk) * D_DIM);
    float4* o4 = (float4*)(out + (size_t)t * D_DIM);
    o4[lane] = w4[lane];
}

extern "C" void kernel_launch(void* const* d_in, const int* in_sizes, int n_in,
                              void* d_out, int out_size, void* d_ws, size_t ws_size,
                              hipStream_t stream) {
    const float* h       = (const float*)d_in[0];
    const float* centers = (const float*)d_in[1];
    const int*   phones  = (const int*)d_in[2];
    float*       out     = (float*)d_out;
    float*       norms   = (float*)d_ws;   // P*K floats = 32 KB scratch

    // 8192 centers, one wave each, 4 waves/block -> 2048 blocks
    qr_norms_kernel<<<(P_PHONES * K_CENT) / 4, 256, 0, stream>>>(centers, norms);
    // 8192 frames, one wave each, 4 waves/block -> 2048 blocks
    qr_retrieve_kernel<<<T_FRAMES / 4, 256, 0, stream>>>(h, centers, phones, norms, out);
}